// Round 3
// baseline (152.573 us; speedup 1.0000x reference)
//
#include <hip/hip_runtime.h>
#include <hip/hip_bf16.h>

typedef __attribute__((ext_vector_type(8))) short bf16x8;
typedef __attribute__((ext_vector_type(4))) float f32x4;
typedef __attribute__((ext_vector_type(16))) float f32x16;

#define MFMA16(a, b, c) __builtin_amdgcn_mfma_f32_16x16x32_bf16(a, b, c, 0, 0, 0)
#define MFMA32(a, b, c) __builtin_amdgcn_mfma_f32_32x32x16_bf16(a, b, c, 0, 0, 0)

static constexpr int kH = 12;
static constexpr int kN = 1024;
static constexpr int kD = 64;
static constexpr int kBH = 96;
static constexpr int kND = kN * kD;            // 65536 per head
static constexpr float kScale = 0.125f;
static constexpr float kEps = 1e-6f;
static constexpr long kTensorElems = (long)kBH * kND;     // 6291456
static constexpr long kWsNeeded = 2 * kTensorElems * 2;   // K + Vt bf16

// ---------- bf16 helpers ----------
__device__ __forceinline__ unsigned bfbits(float x) {
    union { __hip_bfloat16 h; unsigned short u; } c;
    c.h = __float2bfloat16(x);
    return (unsigned)c.u;
}
__device__ __forceinline__ unsigned pack2_rne(float a, float b) {
    return bfbits(a) | (bfbits(b) << 16);
}
// round-half-up pack (operands >= 0 post-ReLU)
__device__ __forceinline__ unsigned pack2_rhu(float lo, float hi) {
    unsigned a = __builtin_bit_cast(unsigned, lo) + 0x8000u;
    unsigned b = __builtin_bit_cast(unsigned, hi) + 0x8000u;
    return __builtin_amdgcn_perm(b, a, 0x07060302u);
}
__device__ __forceinline__ void gl_lds16(const void* g, void* l) {
    __builtin_amdgcn_global_load_lds(
        (const __attribute__((address_space(1))) void*)g,
        (__attribute__((address_space(3))) void*)l, 16, 0, 0);
}

// ---------- prepass: K fp32->bf16 cast + V fp32 [n][d] -> Vt bf16 [d][key-permuted n] ----
// Vt key positions are stored with key bits 2<->3 swapped (kappa involution) so the
// main kernel's PV A-fragments need NO cross-lane exchange (key-permutation-invariant sum).
__global__ __launch_bounds__(256, 2) void prep(
    const float* __restrict__ k, const float* __restrict__ v,
    unsigned* __restrict__ kbf, unsigned* __restrict__ vtb)
{
    static constexpr int TS = 68;
    __shared__ float T32[64 * TS];
    const int bid = blockIdx.x;                   // 1536 = 96 bh * 16 nt
    const int bh = bid >> 4, nt = bid & 15;
    const int t = threadIdx.x;

    const float* kp = k + (long)bh * kND + (long)nt * 64 * kD;
    unsigned* ko = kbf + ((long)bh * kND + (long)nt * 64 * kD) / 2;
#pragma unroll
    for (int r = 0; r < 4; ++r) {
        const int f4 = t + 256 * r;
        const float4 f = ((const float4*)kp)[f4];
        uint2 u;
        u.x = pack2_rne(f.x, f.y);
        u.y = pack2_rne(f.z, f.w);
        *(uint2*)&ko[f4 * 2] = u;
    }

    const float* vp = v + (long)bh * kND + (long)nt * 64 * kD;
#pragma unroll
    for (int r = 0; r < 4; ++r) {
        const int f4 = t + 256 * r;
        const int n = f4 >> 4, d4 = f4 & 15;
        const float4 f = *(const float4*)(vp + (long)n * kD + 4 * d4);
        *(float4*)&T32[n * TS + 4 * d4] = f;
    }
    __syncthreads();
    const int d = t >> 2, c = t & 3;
    unsigned u[8];
#pragma unroll
    for (int j = 0; j < 8; ++j) {
        const int key = c * 16 + 2 * j;
        u[j] = pack2_rne(T32[key * TS + d], T32[(key + 1) * TS + d]);
    }
    unsigned* dst = vtb + (long)bh * (kND / 2) + (long)d * (kN / 2) + nt * 32 + c * 8;
    // key bit2<->bit3 swap permutation: uint cols {0,1,2,3} <- {u0,u1,u4,u5},
    // cols {4,5,6,7} <- {u2,u3,u6,u7}
    uint4 A, B;
    A.x = u[0]; A.y = u[1]; A.z = u[4]; A.w = u[5];
    B.x = u[2]; B.y = u[3]; B.z = u[6]; B.w = u[7];
    *(uint4*)(dst)     = A;
    *(uint4*)(dst + 4) = B;
}

// ---------- main attention kernel: 32x32x16 MFMA, permuted-V, cross-tile pipeline ----------
// grid 768: 128 q-rows/block, 4 waves x 32 q-rows. 64-key tiles.
// Pipeline: poly(t) consumes S^T produced LAST iteration; S(t+1) re-uses the same
// accumulator registers (WAR); PV(t) closes. Poly VALU overlaps the previous body's
// MFMA tail; the S/PV cluster overlaps the co-resident waves' poly.
// K double-buffered, V triple-buffered (vfr(t) is read in the same body that issues
// staging of t+2; Vs[(t+2)%3] != Vs[t%3], and overwrite of Vs[t%3] is issued at body
// t+1, after barrier(t+1) -> no cross-wave race).
__global__ __launch_bounds__(256, 3) void l2q_main(
    const float* __restrict__ q,
    const unsigned short* __restrict__ kbf, const unsigned short* __restrict__ vtbf,
    const float* __restrict__ alpha, const float* __restrict__ beta, const float* __restrict__ gamma,
    float* __restrict__ out)
{
    // K: 64 key-rows x 64 bf16 (32 uints, 8 granules/row, xor-swizzled). V: 64 d-rows x 64 keys.
    __shared__ __align__(16) unsigned Ks[2][2048];
    __shared__ __align__(16) unsigned Vs[3][2048];

    const int bid  = blockIdx.x;
    const int xcd  = bid & 7;                  // XCD head-pinning (FETCH 104->26 MB, R3)
    const int sIdx = bid >> 3;                 // 0..95
    const int bh   = xcd * 12 + (sIdx % 12);
    const int qt   = sIdx / 12;                // 0..7 (128-row q-tiles)
    const int h    = bh % kH;
    const int t    = threadIdx.x;
    const int wave = t >> 6;
    const int lane = t & 63;
    const int l31  = lane & 31;
    const int hh   = lane >> 5;                // half of the wave

    const float al = alpha[h] * (kScale * kScale);
    const float be = beta[h] * kScale;
    const float ga = gamma[h];

    const float* qp = q + (long)bh * kND;
    const unsigned short* kp = kbf + (long)bh * kND;
    const unsigned short* vp = vtbf + (long)bh * kND;   // [d][key-permuted n]

    // Q B-frags (B[k=d][n=q]: n=l31, k = s*16 + hh*8 + j), from fp32 global, once
    bf16x8 qbF[4];
    {
        const int qrow = qt * 128 + wave * 32 + l31;
        const float* qsrc = qp + (long)qrow * kD;
#pragma unroll
        for (int s = 0; s < 4; ++s) {
            const float4 f0 = *(const float4*)(qsrc + s * 16 + hh * 8);
            const float4 f1 = *(const float4*)(qsrc + s * 16 + hh * 8 + 4);
            uint4 u;
            u.x = pack2_rne(f0.x, f0.y);
            u.y = pack2_rne(f0.z, f0.w);
            u.z = pack2_rne(f1.x, f1.y);
            u.w = pack2_rne(f1.z, f1.w);
            qbF[s] = __builtin_bit_cast(bf16x8, u);
        }
    }

    f32x16 oacc[2];
#pragma unroll
    for (int db = 0; db < 2; ++db)
#pragma unroll
        for (int r = 0; r < 16; ++r)
            oacc[db][r] = 0.f;
    float dacc[4] = {0.f, 0.f, 0.f, 0.f};

    // staging geometry (R2-proven): wave fills 8-row 1KB segments; granule g holds chunk g^(row&7)
    const int srow8 = lane >> 3;
    const int g8    = lane & 7;
    auto stageKV = [&](int tile) {
        const int kbuf = tile & 1;
        const int vbuf = tile % 3;
        const int k0 = tile * 64;
#pragma unroll
        for (int c = 0; c < 2; ++c) {
            const int seg = c * 4 + wave;
            const int r = seg * 8 + srow8;          // 0..63
            gl_lds16(kp + (long)(k0 + r) * kD + (g8 ^ srow8) * 8, &Ks[kbuf][seg * 256]);
            gl_lds16(vp + (long)r * kN + k0 + (g8 ^ srow8) * 8, &Vs[vbuf][seg * 256]);
        }
    };

    // ---- prologue: stage tiles 0,1; compute S(0) ----
    stageKV(0);
    stageKV(1);
    __syncthreads();                           // drains vmcnt: tiles 0 and 1 staged

    f32x16 st[2];                              // S^T accumulators, live across iterations
    {
        const unsigned* Kb = Ks[0];
#pragma unroll
        for (int kb = 0; kb < 2; ++kb)
#pragma unroll
            for (int r = 0; r < 16; ++r)
                st[kb][r] = 0.f;
#pragma unroll
        for (int s = 0; s < 4; ++s) {
            const int g = (s << 1) | hh;
#pragma unroll
            for (int kb = 0; kb < 2; ++kb) {
                const int row = kb * 32 + l31;
                bf16x8 ka = *(const bf16x8*)&Kb[row * 32 + ((g ^ (row & 7)) << 2)];
                st[kb] = MFMA32(ka, qbF[s], st[kb]);
            }
        }
    }

    for (int tile = 0; tile < 16; ++tile) {
        // Barrier: (a) staging(tile+1) complete (implicit vmcnt drain, every wave),
        // (b) fences all waves' reads of the buffers stage(tile+2) will overwrite.
        __syncthreads();
        if (tile + 2 < 16) stageKV(tile + 2);

        // ---- V-frag loads for tile (from Vs[tile%3]; staged 2 iterations ago) ----
        const unsigned* Vb = Vs[tile % 3];
        bf16x8 vfr[2][4];
#pragma unroll
        for (int db = 0; db < 2; ++db) {
            const int row = db * 32 + l31;
            const int rb = row * 32;
            const int rsw = row & 7;
#pragma unroll
            for (int s = 0; s < 4; ++s)
                vfr[db][s] = *(const bf16x8*)&Vb[rb + ((((s << 1) | hh) ^ rsw) << 2)];
        }

        // ---- poly(tile) + ReLU + denom + pack, from st produced LAST iteration ----
        // (st results aged through PV(t-1) + barrier + staging + vfr loads: no MFMA wait)
        unsigned u[2][8];
#pragma unroll
        for (int kb = 0; kb < 2; ++kb) {
#pragma unroll
            for (int p = 0; p < 8; ++p) {
                const float s0 = st[kb][2 * p], s1 = st[kb][2 * p + 1];
                const float w0 = fmaxf(fmaf(fmaf(al, s0, be), s0, ga), 0.f);
                const float w1 = fmaxf(fmaf(fmaf(al, s1, be), s1, ga), 0.f);
                dacc[p & 3] += w0 + w1;
                u[kb][p] = pack2_rhu(w0, w1);
            }
        }

        __builtin_amdgcn_s_setprio(1);
        // ---- S(tile+1): K Q^T into the SAME st registers (WAR over poly reads) ----
        if (tile + 1 < 16) {
            const unsigned* Kb = Ks[(tile + 1) & 1];
#pragma unroll
            for (int kb = 0; kb < 2; ++kb)
#pragma unroll
                for (int r = 0; r < 16; ++r)
                    st[kb][r] = 0.f;
#pragma unroll
            for (int s = 0; s < 4; ++s) {
                const int g = (s << 1) | hh;
#pragma unroll
                for (int kb = 0; kb < 2; ++kb) {
                    const int row = kb * 32 + l31;
                    bf16x8 ka = *(const bf16x8*)&Kb[row * 32 + ((g ^ (row & 7)) << 2)];
                    st[kb] = MFMA32(ka, qbF[s], st[kb]);
                }
            }
        }

        // ---- O += P V : A-frag s = u[s>>1][4*(s&1)..+3] directly (kappa-permuted keys
        //      match the kappa-permuted Vt layout; no cross-lane exchange needed) ----
#pragma unroll
        for (int s = 0; s < 4; ++s) {
            uint4 fr;
            const int kb = s >> 1, b = (s & 1) * 4;
            fr.x = u[kb][b + 0];
            fr.y = u[kb][b + 1];
            fr.z = u[kb][b + 2];
            fr.w = u[kb][b + 3];
            const bf16x8 pa = __builtin_bit_cast(bf16x8, fr);
            oacc[0] = MFMA32(pa, vfr[0][s], oacc[0]);
            oacc[1] = MFMA32(pa, vfr[1][s], oacc[1]);
        }
        __builtin_amdgcn_s_setprio(0);
    }

    // ---- denominator (q = l31): in-lane sum + cross-half merge ----
    float d = (dacc[0] + dacc[1]) + (dacc[2] + dacc[3]);
    d += __shfl_xor(d, 32);
    const float inv = 1.0f / (d + kEps);

    // ---- store: C row = (r&3)+8*(r>>2)+4*hh, col = db*32+l31 (full 128B lines) ----
    const long obase = (long)bh * kND;
    const int rowbase = qt * 128 + wave * 32;
#pragma unroll
    for (int r = 0; r < 16; ++r) {
        const int row32 = (r & 3) + 8 * (r >> 2) + 4 * hh;
        const float iv = __shfl(inv, row32);   // inv lives at lane q (both halves valid)
        float* o = out + obase + (long)(rowbase + row32) * kD + l31;
        o[0]  = oacc[0][r] * iv;
        o[32] = oacc[1][r] * iv;
    }
}

// ---------- fallback (fp32 direct) for small ws ----------
static constexpr int KSU = 36;
static constexpr int VSU = 36;
static constexpr int PSU = 36;

__global__ __launch_bounds__(256, 3) void l2q_attn_fb(
    const float* __restrict__ q, const float* __restrict__ k, const float* __restrict__ v,
    const float* __restrict__ alpha, const float* __restrict__ beta, const float* __restrict__ gamma,
    float* __restrict__ out)
{
    __shared__ __align__(16) unsigned KsU[64 * KSU];
    __shared__ __align__(16) unsigned VtU[64 * VSU];
    __shared__ __align__(16) unsigned PU[128 * PSU];

    const int bid  = blockIdx.x;
    const int bh   = bid >> 3;
    const int qt   = bid & 7;
    const int h    = bh % kH;
    const int t    = threadIdx.x;
    const int wave = t >> 6;
    const int lane = t & 63;
    const int quad = lane >> 4;
    const int l15  = lane & 15;

    const float al = alpha[h], be = beta[h], ga = gamma[h];

    const long base = (long)bh * kN * kD;
    const float* qp = q + base;
    const float* kp = k + base;
    const float* vp = v + base;

    bf16x8 qa[2][2];
#pragma unroll
    for (int rb = 0; rb < 2; ++rb) {
        const int row = qt * 128 + wave * 32 + rb * 16 + l15;
#pragma unroll
        for (int kc = 0; kc < 2; ++kc) {
            const float* src = qp + (long)row * kD + kc * 32 + quad * 8;
            const float4 f0 = *(const float4*)(src);
            const float4 f1 = *(const float4*)(src + 4);
            uint4 u;
            u.x = pack2_rne(f0.x, f0.y);
            u.y = pack2_rne(f0.z, f0.w);
            u.z = pack2_rne(f1.x, f1.y);
            u.w = pack2_rne(f1.z, f1.w);
            qa[rb][kc] = __builtin_bit_cast(bf16x8, u);
        }
    }

    f32x4 oacc[2][4];
#pragma unroll
    for (int rb = 0; rb < 2; ++rb)
#pragma unroll
        for (int db = 0; db < 4; ++db)
            oacc[rb][db] = (f32x4){0.f, 0.f, 0.f, 0.f};

    float dsum[2][4] = {{0.f, 0.f, 0.f, 0.f}, {0.f, 0.f, 0.f, 0.f}};
    unsigned* Pw = &PU[wave * 32 * PSU];

    for (int tile = 0; tile < 16; ++tile) {
        __syncthreads();
        const int k0 = tile * 64;
#pragma unroll
        for (int r = 0; r < 4; ++r) {
            const int f4 = t + 256 * r;
            const int n = f4 >> 4, d4 = f4 & 15;
            const float4 kg = *(const float4*)(kp + (long)(k0 + n) * kD + 4 * d4);
            uint2 pk;
            pk.x = pack2_rne(kg.x, kg.y);
            pk.y = pack2_rne(kg.z, kg.w);
            *(uint2*)&KsU[n * KSU + 2 * d4] = pk;
        }
#pragma unroll
        for (int r = 0; r < 2; ++r) {
            const int u = t + 256 * r;
            const int key2 = u & 31, d4 = u >> 5;
            const float* s0 = vp + (long)(k0 + 2 * key2) * kD + 4 * d4;
            const float4 va = *(const float4*)(s0);
            const float4 vb = *(const float4*)(s0 + kD);
            VtU[(4 * d4 + 0) * VSU + key2] = pack2_rne(va.x, vb.x);
            VtU[(4 * d4 + 1) * VSU + key2] = pack2_rne(va.y, vb.y);
            VtU[(4 * d4 + 2) * VSU + key2] = pack2_rne(va.z, vb.z);
            VtU[(4 * d4 + 3) * VSU + key2] = pack2_rne(va.w, vb.w);
        }
        __syncthreads();

        f32x4 s[2][4];
#pragma unroll
        for (int rb = 0; rb < 2; ++rb)
#pragma unroll
            for (int nb = 0; nb < 4; ++nb)
                s[rb][nb] = (f32x4){0.f, 0.f, 0.f, 0.f};
#pragma unroll
        for (int nb = 0; nb < 4; ++nb) {
            bf16x8 kb0 = *(const bf16x8*)&KsU[(nb * 16 + l15) * KSU + 4 * quad];
            bf16x8 kb1 = *(const bf16x8*)&KsU[(nb * 16 + l15) * KSU + 16 + 4 * quad];
#pragma unroll
            for (int rb = 0; rb < 2; ++rb) {
                s[rb][nb] = MFMA16(qa[rb][0], kb0, s[rb][nb]);
                s[rb][nb] = MFMA16(qa[rb][1], kb1, s[rb][nb]);
            }
        }

        const bool ev = (lane & 1) == 0;
#pragma unroll
        for (int rb = 0; rb < 2; ++rb) {
#pragma unroll
            for (int nb = 0; nb < 4; ++nb) {
                float w0, w1, w2, w3;
                {
                    float l0 = s[rb][nb][0] * kScale;
                    float l1 = s[rb][nb][1] * kScale;
                    float l2 = s[rb][nb][2] * kScale;
                    float l3 = s[rb][nb][3] * kScale;
                    w0 = fmaxf(fmaf(fmaf(al, l0, be), l0, ga), 0.f);
                    w1 = fmaxf(fmaf(fmaf(al, l1, be), l1, ga), 0.f);
                    w2 = fmaxf(fmaf(fmaf(al, l2, be), l2, ga), 0.f);
                    w3 = fmaxf(fmaf(fmaf(al, l3, be), l3, ga), 0.f);
                }
                dsum[rb][0] += w0; dsum[rb][1] += w1;
                dsum[rb][2] += w2; dsum[rb][3] += w3;

                const float o0 = __shfl_xor(w0, 1);
                const float o1 = __shfl_xor(w1, 1);
                const float o2 = __shfl_xor(w2, 1);
                const float o3 = __shfl_xor(w3, 1);
                const unsigned pa = ev ? pack2_rne(w0, o0) : pack2_rne(o2, w2);
                const unsigned pb = ev ? pack2_rne(w1, o1) : pack2_rne(o3, w3);
                const int r0 = ev ? 0 : 2;
                const int cu = (16 * nb + (l15 & ~1)) >> 1;
                const int rowb = rb * 16 + quad * 4 + r0;
                Pw[rowb * PSU + cu] = pa;
                Pw[(rowb + 1) * PSU + cu] = pb;
            }
        }

        bf16x8 pf[2][2];
#pragma unroll
        for (int rb = 0; rb < 2; ++rb)
#pragma unroll
            for (int kc = 0; kc < 2; ++kc)
                pf[rb][kc] = *(const bf16x8*)&Pw[(rb * 16 + l15) * PSU + 16 * kc + 4 * quad];
#pragma unroll
        for (int db = 0; db < 4; ++db) {
            bf16x8 vf0 = *(const bf16x8*)&VtU[(db * 16 + l15) * VSU + 4 * quad];
            bf16x8 vf1 = *(const bf16x8*)&VtU[(db * 16 + l15) * VSU + 16 + 4 * quad];
#pragma unroll
            for (int rb = 0; rb < 2; ++rb) {
                oacc[rb][db] = MFMA16(pf[rb][0], vf0, oacc[rb][db]);
                oacc[rb][db] = MFMA16(pf[rb][1], vf1, oacc[rb][db]);
            }
        }
    }

#pragma unroll
    for (int rb = 0; rb < 2; ++rb)
#pragma unroll
        for (int i = 0; i < 4; ++i) {
            float d = dsum[rb][i];
            d += __shfl_xor(d, 1);
            d += __shfl_xor(d, 2);
            d += __shfl_xor(d, 4);
            d += __shfl_xor(d, 8);
            dsum[rb][i] = 1.0f / (d + kEps);
        }

#pragma unroll
    for (int rb = 0; rb < 2; ++rb)
#pragma unroll
        for (int db = 0; db < 4; ++db)
#pragma unroll
            for (int i = 0; i < 4; ++i) {
                const int row = qt * 128 + wave * 32 + rb * 16 + quad * 4 + i;
                out[base + (long)row * kD + db * 16 + l15] = oacc[rb][db][i] * dsum[rb][i];
            }
}

extern "C" void kernel_launch(void* const* d_in, const int* in_sizes, int n_in,
                              void* d_out, int out_size, void* d_ws, size_t ws_size,
                              hipStream_t stream) {
    const float* q     = (const float*)d_in[0];
    const float* k     = (const float*)d_in[1];
    const float* v     = (const float*)d_in[2];
    const float* alpha = (const float*)d_in[3];
    const float* beta  = (const float*)d_in[4];
    const float* gamma = (const float*)d_in[5];
    float* out = (float*)d_out;

    if (ws_size < (size_t)kWsNeeded) {
        l2q_attn_fb<<<dim3(768), dim3(256), 0, stream>>>(q, k, v, alpha, beta, gamma, out);
        return;
    }

    unsigned* kbf = (unsigned*)d_ws;
    unsigned* vtb = kbf + kTensorElems / 2;

    prep<<<dim3(1536), dim3(256), 0, stream>>>(k, v, kbf, vtb);
    l2q_main<<<dim3(768), dim3(256), 0, stream>>>(
        q, (const unsigned short*)kbf, (const unsigned short*)vtb,
        alpha, beta, gamma, out);
}

// Round 4
// 145.340 us; speedup vs baseline: 1.0498x; 1.0498x over previous
//
#include <hip/hip_runtime.h>
#include <hip/hip_bf16.h>

typedef __attribute__((ext_vector_type(8))) short bf16x8;
typedef __attribute__((ext_vector_type(4))) float f32x4;
typedef __attribute__((ext_vector_type(16))) float f32x16;

#define MFMA16(a, b, c) __builtin_amdgcn_mfma_f32_16x16x32_bf16(a, b, c, 0, 0, 0)
#define MFMA32(a, b, c) __builtin_amdgcn_mfma_f32_32x32x16_bf16(a, b, c, 0, 0, 0)

static constexpr int kH = 12;
static constexpr int kN = 1024;
static constexpr int kD = 64;
static constexpr int kBH = 96;
static constexpr int kND = kN * kD;            // 65536 per head
static constexpr float kScale = 0.125f;
static constexpr float kEps = 1e-6f;
static constexpr long kTensorElems = (long)kBH * kND;     // 6291456
static constexpr long kWsNeeded = 2 * kTensorElems * 2;   // K + Vlin bf16

// ---------- bf16 helpers ----------
__device__ __forceinline__ unsigned bfbits(float x) {
    union { __hip_bfloat16 h; unsigned short u; } c;
    c.h = __float2bfloat16(x);
    return (unsigned)c.u;
}
__device__ __forceinline__ unsigned pack2_rne(float a, float b) {
    return bfbits(a) | (bfbits(b) << 16);
}
// round-half-up pack (operands >= 0 post-ReLU)
__device__ __forceinline__ unsigned pack2_rhu(float lo, float hi) {
    unsigned a = __builtin_bit_cast(unsigned, lo) + 0x8000u;
    unsigned b = __builtin_bit_cast(unsigned, hi) + 0x8000u;
    return __builtin_amdgcn_perm(b, a, 0x07060302u);
}
__device__ __forceinline__ void gl_lds16(const void* g, void* l) {
    __builtin_amdgcn_global_load_lds(
        (const __attribute__((address_space(1))) void*)g,
        (__attribute__((address_space(3))) void*)l, 16, 0, 0);
}

// ---------- prepass: K fp32->bf16 cast + V fp32 [n][d] -> Vlin bf16 fragment-major ----
// Vlin layout (per head, uints): [tile(16)][db*4+s (8)][lane=hh*32+l31 (64)][j (4)]
//   = tile*2048 + (db*4+s)*256 + lane*4 + j
// Each main-kernel V-frag load (db,s) is then 64 lanes x 16B CONTIGUOUS (1KB coalesced).
// Key positions inside each granule keep the kappa (bit2<->3 swap) involution so PV's
// A-fragments need no cross-lane exchange (same bits to same lanes as the LDS version).
__global__ __launch_bounds__(256, 2) void prep(
    const float* __restrict__ k, const float* __restrict__ v,
    unsigned* __restrict__ kbf, unsigned* __restrict__ vtb)
{
    static constexpr int TS = 68;
    __shared__ float T32[64 * TS];
    const int bid = blockIdx.x;                   // 1536 = 96 bh * 16 nt
    const int bh = bid >> 4, nt = bid & 15;
    const int t = threadIdx.x;

    const float* kp = k + (long)bh * kND + (long)nt * 64 * kD;
    unsigned* ko = kbf + ((long)bh * kND + (long)nt * 64 * kD) / 2;
#pragma unroll
    for (int r = 0; r < 4; ++r) {
        const int f4 = t + 256 * r;
        const float4 f = ((const float4*)kp)[f4];
        uint2 u;
        u.x = pack2_rne(f.x, f.y);
        u.y = pack2_rne(f.z, f.w);
        *(uint2*)&ko[f4 * 2] = u;
    }

    const float* vp = v + (long)bh * kND + (long)nt * 64 * kD;
#pragma unroll
    for (int r = 0; r < 4; ++r) {
        const int f4 = t + 256 * r;
        const int n = f4 >> 4, d4 = f4 & 15;
        const float4 f = *(const float4*)(vp + (long)n * kD + 4 * d4);
        *(float4*)&T32[n * TS + 4 * d4] = f;
    }
    __syncthreads();
    const int d = t >> 2, c = t & 3;              // d: 0..63 (output dim), c: 0..3
    unsigned u[8];
#pragma unroll
    for (int j = 0; j < 8; ++j) {
        const int key = c * 16 + 2 * j;
        u[j] = pack2_rne(T32[key * TS + d], T32[(key + 1) * TS + d]);
    }
    // kappa permutation: granule 2c (hh=0) holds {u0,u1,u4,u5}, granule 2c+1 (hh=1)
    // holds {u2,u3,u6,u7} (key bit2<->bit3 swap).
    uint4 A, B;
    A.x = u[0]; A.y = u[1]; A.z = u[4]; A.w = u[5];
    B.x = u[2]; B.y = u[3]; B.z = u[6]; B.w = u[7];
    // fragment-major destination: s = c, db = d>>5, l31 = d&31
    unsigned* vbase = vtb + (long)bh * (kND / 2);
    const long o0 = (long)nt * 2048 + ((d >> 5) * 4 + c) * 256 + (d & 31) * 4;
    *(uint4*)(vbase + o0)       = A;              // hh = 0
    *(uint4*)(vbase + o0 + 128) = B;              // hh = 1 (+32 lanes * 4 uints)
}

// ---------- main attention kernel: 32x32x16 MFMA, K via LDS dbuf, V direct from L2 ----------
// grid 768: 128 q-rows/block, 4 waves x 32 q-rows. 64-key tiles, 1 barrier/tile.
// V is NOT staged in LDS: per head K+V = 256KB is L2-resident under XCD head-pinning,
// and the fragment-major Vlin layout makes each V-frag a fully-coalesced 1KB global load
// issued right after the barrier and consumed ~800cy later at PV (L2 latency hidden).
__global__ __launch_bounds__(256, 3) void l2q_main(
    const float* __restrict__ q,
    const unsigned short* __restrict__ kbf, const unsigned short* __restrict__ vtbf,
    const float* __restrict__ alpha, const float* __restrict__ beta, const float* __restrict__ gamma,
    float* __restrict__ out)
{
    // K: 64 key-rows x 64 bf16 (32 uints, 8 granules/row, xor-swizzled), double-buffered.
    __shared__ __align__(16) unsigned Ks[2][2048];

    const int bid  = blockIdx.x;
    const int xcd  = bid & 7;                  // XCD head-pinning (FETCH 104->26 MB, R3)
    const int sIdx = bid >> 3;                 // 0..95
    const int bh   = xcd * 12 + (sIdx % 12);
    const int qt   = sIdx / 12;                // 0..7 (128-row q-tiles)
    const int h    = bh % kH;
    const int t    = threadIdx.x;
    const int wave = t >> 6;
    const int lane = t & 63;
    const int l31  = lane & 31;
    const int hh   = lane >> 5;                // half of the wave

    const float al = alpha[h] * (kScale * kScale);
    const float be = beta[h] * kScale;
    const float ga = gamma[h];

    const float* qp = q + (long)bh * kND;
    const unsigned short* kp = kbf + (long)bh * kND;
    const unsigned* vlin = (const unsigned*)vtbf + (long)bh * (kND / 2);

    // Q B-frags (B[k=d][n=q]: n=l31, k = s*16 + hh*8 + j), from fp32 global, once
    bf16x8 qbF[4];
    {
        const int qrow = qt * 128 + wave * 32 + l31;
        const float* qsrc = qp + (long)qrow * kD;
#pragma unroll
        for (int s = 0; s < 4; ++s) {
            const float4 f0 = *(const float4*)(qsrc + s * 16 + hh * 8);
            const float4 f1 = *(const float4*)(qsrc + s * 16 + hh * 8 + 4);
            uint4 u;
            u.x = pack2_rne(f0.x, f0.y);
            u.y = pack2_rne(f0.z, f0.w);
            u.z = pack2_rne(f1.x, f1.y);
            u.w = pack2_rne(f1.z, f1.w);
            qbF[s] = __builtin_bit_cast(bf16x8, u);
        }
    }

    f32x16 oacc[2];
#pragma unroll
    for (int db = 0; db < 2; ++db)
#pragma unroll
        for (int r = 0; r < 16; ++r)
            oacc[db][r] = 0.f;
    float dacc[4] = {0.f, 0.f, 0.f, 0.f};

    // K staging geometry (R2-proven): wave fills 8-row 1KB segments; granule g holds
    // chunk g^(row&7)
    const int srow8 = lane >> 3;
    const int g8    = lane & 7;
    auto stageK = [&](int buf, int tile) {
        const int k0 = tile * 64;
#pragma unroll
        for (int c = 0; c < 2; ++c) {
            const int seg = c * 4 + wave;
            const int r = seg * 8 + srow8;          // 0..63
            gl_lds16(kp + (long)(k0 + r) * kD + (g8 ^ srow8) * 8, &Ks[buf][seg * 256]);
        }
    };

    stageK(0, 0);

    for (int tile = 0; tile < 16; ++tile) {
        const int buf = tile & 1;
        __syncthreads();                       // drains vmcnt: this tile's K staged
        if (tile + 1 < 16) stageK(buf ^ 1, tile + 1);

        // ---- V-frag loads for this tile: direct global (L2-hit), fully coalesced.
        //      Issued here so S-MFMA + poly (~800cy) cover the ~200cy L2 latency. ----
        const unsigned* vt0 = vlin + (long)tile * 2048 + (hh * 32 + l31) * 4;
        bf16x8 vfr[2][4];
#pragma unroll
        for (int db = 0; db < 2; ++db)
#pragma unroll
            for (int s = 0; s < 4; ++s)
                vfr[db][s] = *(const bf16x8*)(vt0 + (db * 4 + s) * 256);

        const unsigned* Kb = Ks[buf];

        // ---- S^T = K Q^T : two 32-key blocks; C: col=q=l31, row=key=(r&3)+8*(r>>2)+4*hh ----
        f32x16 st[2];
#pragma unroll
        for (int kb = 0; kb < 2; ++kb)
#pragma unroll
            for (int r = 0; r < 16; ++r)
                st[kb][r] = 0.f;
#pragma unroll
        for (int s = 0; s < 4; ++s) {
            const int g = (s << 1) | hh;       // logical granule of A-frag (8 bf16 of d)
#pragma unroll
            for (int kb = 0; kb < 2; ++kb) {
                const int row = kb * 32 + l31;
                bf16x8 ka = *(const bf16x8*)&Kb[row * 32 + ((g ^ (row & 7)) << 2)];
                st[kb] = MFMA32(ka, qbF[s], st[kb]);
            }
        }

        // ---- poly + ReLU + denom + pack to bf16 uints (all in-lane, q = l31) ----
        unsigned u[2][8];
#pragma unroll
        for (int kb = 0; kb < 2; ++kb) {
#pragma unroll
            for (int p = 0; p < 8; ++p) {
                const float s0 = st[kb][2 * p], s1 = st[kb][2 * p + 1];
                const float w0 = fmaxf(fmaf(fmaf(al, s0, be), s0, ga), 0.f);
                const float w1 = fmaxf(fmaf(fmaf(al, s1, be), s1, ga), 0.f);
                dacc[p & 3] += w0 + w1;
                u[kb][p] = pack2_rhu(w0, w1);
            }
        }

        // ---- O += P V : A-frag s = u[s>>1][4*(s&1)..+3] directly (kappa-permuted keys
        //      match the kappa-permuted Vlin granules; no cross-lane exchange needed) ----
#pragma unroll
        for (int s = 0; s < 4; ++s) {
            uint4 fr;
            const int kb = s >> 1, b = (s & 1) * 4;
            fr.x = u[kb][b + 0];
            fr.y = u[kb][b + 1];
            fr.z = u[kb][b + 2];
            fr.w = u[kb][b + 3];
            const bf16x8 pa = __builtin_bit_cast(bf16x8, fr);
            oacc[0] = MFMA32(pa, vfr[0][s], oacc[0]);
            oacc[1] = MFMA32(pa, vfr[1][s], oacc[1]);
        }
    }

    // ---- denominator (q = l31): in-lane sum + cross-half merge ----
    float d = (dacc[0] + dacc[1]) + (dacc[2] + dacc[3]);
    d += __shfl_xor(d, 32);
    const float inv = 1.0f / (d + kEps);

    // ---- store: C row = (r&3)+8*(r>>2)+4*hh, col = db*32+l31 (full 128B lines) ----
    const long obase = (long)bh * kND;
    const int rowbase = qt * 128 + wave * 32;
#pragma unroll
    for (int r = 0; r < 16; ++r) {
        const int row32 = (r & 3) + 8 * (r >> 2) + 4 * hh;
        const float iv = __shfl(inv, row32);   // inv lives at lane q (both halves valid)
        float* o = out + obase + (long)(rowbase + row32) * kD + l31;
        o[0]  = oacc[0][r] * iv;
        o[32] = oacc[1][r] * iv;
    }
}

// ---------- fallback (fp32 direct) for small ws ----------
static constexpr int KSU = 36;
static constexpr int VSU = 36;
static constexpr int PSU = 36;

__global__ __launch_bounds__(256, 3) void l2q_attn_fb(
    const float* __restrict__ q, const float* __restrict__ k, const float* __restrict__ v,
    const float* __restrict__ alpha, const float* __restrict__ beta, const float* __restrict__ gamma,
    float* __restrict__ out)
{
    __shared__ __align__(16) unsigned KsU[64 * KSU];
    __shared__ __align__(16) unsigned VtU[64 * VSU];
    __shared__ __align__(16) unsigned PU[128 * PSU];

    const int bid  = blockIdx.x;
    const int bh   = bid >> 3;
    const int qt   = bid & 7;
    const int h    = bh % kH;
    const int t    = threadIdx.x;
    const int wave = t >> 6;
    const int lane = t & 63;
    const int quad = lane >> 4;
    const int l15  = lane & 15;

    const float al = alpha[h], be = beta[h], ga = gamma[h];

    const long base = (long)bh * kN * kD;
    const float* qp = q + base;
    const float* kp = k + base;
    const float* vp = v + base;

    bf16x8 qa[2][2];
#pragma unroll
    for (int rb = 0; rb < 2; ++rb) {
        const int row = qt * 128 + wave * 32 + rb * 16 + l15;
#pragma unroll
        for (int kc = 0; kc < 2; ++kc) {
            const float* src = qp + (long)row * kD + kc * 32 + quad * 8;
            const float4 f0 = *(const float4*)(src);
            const float4 f1 = *(const float4*)(src + 4);
            uint4 u;
            u.x = pack2_rne(f0.x, f0.y);
            u.y = pack2_rne(f0.z, f0.w);
            u.z = pack2_rne(f1.x, f1.y);
            u.w = pack2_rne(f1.z, f1.w);
            qa[rb][kc] = __builtin_bit_cast(bf16x8, u);
        }
    }

    f32x4 oacc[2][4];
#pragma unroll
    for (int rb = 0; rb < 2; ++rb)
#pragma unroll
        for (int db = 0; db < 4; ++db)
            oacc[rb][db] = (f32x4){0.f, 0.f, 0.f, 0.f};

    float dsum[2][4] = {{0.f, 0.f, 0.f, 0.f}, {0.f, 0.f, 0.f, 0.f}};
    unsigned* Pw = &PU[wave * 32 * PSU];

    for (int tile = 0; tile < 16; ++tile) {
        __syncthreads();
        const int k0 = tile * 64;
#pragma unroll
        for (int r = 0; r < 4; ++r) {
            const int f4 = t + 256 * r;
            const int n = f4 >> 4, d4 = f4 & 15;
            const float4 kg = *(const float4*)(kp + (long)(k0 + n) * kD + 4 * d4);
            uint2 pk;
            pk.x = pack2_rne(kg.x, kg.y);
            pk.y = pack2_rne(kg.z, kg.w);
            *(uint2*)&KsU[n * KSU + 2 * d4] = pk;
        }
#pragma unroll
        for (int r = 0; r < 2; ++r) {
            const int u = t + 256 * r;
            const int key2 = u & 31, d4 = u >> 5;
            const float* s0 = vp + (long)(k0 + 2 * key2) * kD + 4 * d4;
            const float4 va = *(const float4*)(s0);
            const float4 vb = *(const float4*)(s0 + kD);
            VtU[(4 * d4 + 0) * VSU + key2] = pack2_rne(va.x, vb.x);
            VtU[(4 * d4 + 1) * VSU + key2] = pack2_rne(va.y, vb.y);
            VtU[(4 * d4 + 2) * VSU + key2] = pack2_rne(va.z, vb.z);
            VtU[(4 * d4 + 3) * VSU + key2] = pack2_rne(va.w, vb.w);
        }
        __syncthreads();

        f32x4 s[2][4];
#pragma unroll
        for (int rb = 0; rb < 2; ++rb)
#pragma unroll
            for (int nb = 0; nb < 4; ++nb)
                s[rb][nb] = (f32x4){0.f, 0.f, 0.f, 0.f};
#pragma unroll
        for (int nb = 0; nb < 4; ++nb) {
            bf16x8 kb0 = *(const bf16x8*)&KsU[(nb * 16 + l15) * KSU + 4 * quad];
            bf16x8 kb1 = *(const bf16x8*)&KsU[(nb * 16 + l15) * KSU + 16 + 4 * quad];
#pragma unroll
            for (int rb = 0; rb < 2; ++rb) {
                s[rb][nb] = MFMA16(qa[rb][0], kb0, s[rb][nb]);
                s[rb][nb] = MFMA16(qa[rb][1], kb1, s[rb][nb]);
            }
        }

        const bool ev = (lane & 1) == 0;
#pragma unroll
        for (int rb = 0; rb < 2; ++rb) {
#pragma unroll
            for (int nb = 0; nb < 4; ++nb) {
                float w0, w1, w2, w3;
                {
                    float l0 = s[rb][nb][0] * kScale;
                    float l1 = s[rb][nb][1] * kScale;
                    float l2 = s[rb][nb][2] * kScale;
                    float l3 = s[rb][nb][3] * kScale;
                    w0 = fmaxf(fmaf(fmaf(al, l0, be), l0, ga), 0.f);
                    w1 = fmaxf(fmaf(fmaf(al, l1, be), l1, ga), 0.f);
                    w2 = fmaxf(fmaf(fmaf(al, l2, be), l2, ga), 0.f);
                    w3 = fmaxf(fmaf(fmaf(al, l3, be), l3, ga), 0.f);
                }
                dsum[rb][0] += w0; dsum[rb][1] += w1;
                dsum[rb][2] += w2; dsum[rb][3] += w3;

                const float o0 = __shfl_xor(w0, 1);
                const float o1 = __shfl_xor(w1, 1);
                const float o2 = __shfl_xor(w2, 1);
                const float o3 = __shfl_xor(w3, 1);
                const unsigned pa = ev ? pack2_rne(w0, o0) : pack2_rne(o2, w2);
                const unsigned pb = ev ? pack2_rne(w1, o1) : pack2_rne(o3, w3);
                const int r0 = ev ? 0 : 2;
                const int cu = (16 * nb + (l15 & ~1)) >> 1;
                const int rowb = rb * 16 + quad * 4 + r0;
                Pw[rowb * PSU + cu] = pa;
                Pw[(rowb + 1) * PSU + cu] = pb;
            }
        }

        bf16x8 pf[2][2];
#pragma unroll
        for (int rb = 0; rb < 2; ++rb)
#pragma unroll
            for (int kc = 0; kc < 2; ++kc)
                pf[rb][kc] = *(const bf16x8*)&Pw[(rb * 16 + l15) * PSU + 16 * kc + 4 * quad];
#pragma unroll
        for (int db = 0; db < 4; ++db) {
            bf16x8 vf0 = *(const bf16x8*)&VtU[(db * 16 + l15) * VSU + 4 * quad];
            bf16x8 vf1 = *(const bf16x8*)&VtU[(db * 16 + l15) * VSU + 16 + 4 * quad];
#pragma unroll
            for (int rb = 0; rb < 2; ++rb) {
                oacc[rb][db] = MFMA16(pf[rb][0], vf0, oacc[rb][db]);
                oacc[rb][db] = MFMA16(pf[rb][1], vf1, oacc[rb][db]);
            }
        }
    }

#pragma unroll
    for (int rb = 0; rb < 2; ++rb)
#pragma unroll
        for (int i = 0; i < 4; ++i) {
            float d = dsum[rb][i];
            d += __shfl_xor(d, 1);
            d += __shfl_xor(d, 2);
            d += __shfl_xor(d, 4);
            d += __shfl_xor(d, 8);
            dsum[rb][i] = 1.0f / (d + kEps);
        }

#pragma unroll
    for (int rb = 0; rb < 2; ++rb)
#pragma unroll
        for (int db = 0; db < 4; ++db)
#pragma unroll
            for (int i = 0; i < 4; ++i) {
                const int row = qt * 128 + wave * 32 + rb * 16 + quad * 4 + i;
                out[base + (long)row * kD + db * 16 + l15] = oacc[rb][db][i] * dsum[rb][i];
            }
}

extern "C" void kernel_launch(void* const* d_in, const int* in_sizes, int n_in,
                              void* d_out, int out_size, void* d_ws, size_t ws_size,
                              hipStream_t stream) {
    const float* q     = (const float*)d_in[0];
    const float* k     = (const float*)d_in[1];
    const float* v     = (const float*)d_in[2];
    const float* alpha = (const float*)d_in[3];
    const float* beta  = (const float*)d_in[4];
    const float* gamma = (const float*)d_in[5];
    float* out = (float*)d_out;

    if (ws_size < (size_t)kWsNeeded) {
        l2q_attn_fb<<<dim3(768), dim3(256), 0, stream>>>(q, k, v, alpha, beta, gamma, out);
        return;
    }

    unsigned* kbf = (unsigned*)d_ws;
    unsigned* vtb = kbf + kTensorElems / 2;

    prep<<<dim3(1536), dim3(256), 0, stream>>>(k, v, kbf, vtb);
    l2q_main<<<dim3(768), dim3(256), 0, stream>>>(
        q, (const unsigned short*)kbf, (const unsigned short*)vtb,
        alpha, beta, gamma, out);
}